// Round 1
// baseline (4237.181 us; speedup 1.0000x reference)
//
#include <hip/hip_runtime.h>
#include <math.h>

#define BSZ 2
#define SEQ 2048
#define DIM 2048
#define NH 32
#define NKV 8
#define HD 64
#define KVDIM 512   // NKV*HD

// ---------------------------------------------------------------------------
// NT GEMM: C[m,n] = sum_k A[m,k] * W[n,k]
// A: [M,K] row-major, W: [N,K] row-major, C: [M,N] row-major.
// 64x64 tile, K-step 16, 256 threads, 4x4 micro-tile per thread.
// LDS tiles stored k-major ([k][m]/[k][n], row pad 68 words = 272B, 16B-mult)
// so the inner loop is two ds_read_b128 + 16 v_fma per k-step.
// ---------------------------------------------------------------------------
#define GT 64
#define GK 16
#define GP 68

__global__ __launch_bounds__(256) void gemm_nt(const float* __restrict__ A,
                                               const float* __restrict__ W,
                                               float* __restrict__ C,
                                               int M, int N, int K) {
    __shared__ __align__(16) float As[GK][GP];
    __shared__ __align__(16) float Bs[GK][GP];
    const int tid = threadIdx.x;
    const int tx = tid & 15, ty = tid >> 4;
    const int n0 = blockIdx.x * GT;
    const int m0 = blockIdx.y * GT;
    const int lrow = tid >> 2;          // 0..63
    const int lk4 = (tid & 3) << 2;     // 0,4,8,12
    float acc[4][4] = {{0.f, 0.f, 0.f, 0.f}};

    for (int kb = 0; kb < K; kb += GK) {
        float4 av = *(const float4*)(A + (size_t)(m0 + lrow) * K + kb + lk4);
        float4 wv = *(const float4*)(W + (size_t)(n0 + lrow) * K + kb + lk4);
        __syncthreads();  // protect previous iteration's reads
        As[lk4 + 0][lrow] = av.x; As[lk4 + 1][lrow] = av.y;
        As[lk4 + 2][lrow] = av.z; As[lk4 + 3][lrow] = av.w;
        Bs[lk4 + 0][lrow] = wv.x; Bs[lk4 + 1][lrow] = wv.y;
        Bs[lk4 + 2][lrow] = wv.z; Bs[lk4 + 3][lrow] = wv.w;
        __syncthreads();
#pragma unroll
        for (int kk = 0; kk < GK; ++kk) {
            float4 a4 = *(const float4*)&As[kk][ty << 2];
            float4 b4 = *(const float4*)&Bs[kk][tx << 2];
            float a[4] = {a4.x, a4.y, a4.z, a4.w};
            float b[4] = {b4.x, b4.y, b4.z, b4.w};
#pragma unroll
            for (int i = 0; i < 4; ++i)
#pragma unroll
                for (int j = 0; j < 4; ++j)
                    acc[i][j] = fmaf(a[i], b[j], acc[i][j]);
        }
    }
#pragma unroll
    for (int i = 0; i < 4; ++i) {
        float4 o = {acc[i][0], acc[i][1], acc[i][2], acc[i][3]};
        *(float4*)(C + (size_t)(m0 + (ty << 2) + i) * N + n0 + (tx << 2)) = o;
    }
}

// ---------------------------------------------------------------------------
// RoPE in-place on X: [BSZ, SEQ, heads, HD].
// out[d]    = x[d]*cos[s,d]    - x[d+32]*sin[s,d]
// out[d+32] = x[d+32]*cos[s,d+32] + x[d]*sin[s,d+32]
// ---------------------------------------------------------------------------
__global__ __launch_bounds__(256) void rope_kernel(float* __restrict__ X,
                                                   const float* __restrict__ cosT,
                                                   const float* __restrict__ sinT,
                                                   int heads, int total) {
    int idx = blockIdx.x * 256 + threadIdx.x;
    if (idx >= total) return;
    int d = idx & 31;
    int rh = idx >> 5;                      // (b*SEQ + s)*heads + h
    int s = (rh / heads) & (SEQ - 1);
    size_t base = (size_t)rh * HD;
    float x1 = X[base + d], x2 = X[base + d + 32];
    float c1 = cosT[s * HD + d], s1 = sinT[s * HD + d];
    float c2 = cosT[s * HD + d + 32], s2 = sinT[s * HD + d + 32];
    X[base + d] = fmaf(x1, c1, -x2 * s1);
    X[base + d + 32] = fmaf(x2, c2, x1 * s2);
}

// ---------------------------------------------------------------------------
// fp32 flash attention, causal, GQA.
// Q: [B,S,NH,HD] (row stride DIM), K/V: [B,S,NKV,HD] (row stride KVDIM),
// O: [B,S,NH,HD] (=[B,S,DIM]).
// Block: 256 threads = 16x16 thread grid, 4x4 micro-tile; Q-tile 64 rows;
// key tiles of 64, only kt <= qt visited. Online softmax in LDS.
// ---------------------------------------------------------------------------
#define BQ 64
#define BK 64
#define AP 68

__global__ __launch_bounds__(256) void flash_attn(const float* __restrict__ Q,
                                                  const float* __restrict__ K,
                                                  const float* __restrict__ V,
                                                  float* __restrict__ O) {
    __shared__ __align__(16) float Qs[HD][AP];   // [d][qrow]
    __shared__ __align__(16) float Ks[HD][AP];   // [d][krow]
    __shared__ __align__(16) float Vs[BK][AP];   // [krow][d]
    __shared__ __align__(16) float Ps[BK][AP];   // [krow][qrow]
    __shared__ float red[BQ][17];
    __shared__ float m_s[BQ], l_s[BQ], al_s[BQ];

    const int qt = blockIdx.x;
    const int bh = blockIdx.y;
    const int b = bh >> 5, h = bh & 31;
    const int kvh = h >> 2;                  // NREP = 4
    const int tid = threadIdx.x;
    const int tx = tid & 15, ty = tid >> 4;

    const float* Qb = Q + (size_t)b * SEQ * DIM + (size_t)h * HD;
    const float* Kb = K + (size_t)b * SEQ * KVDIM + (size_t)kvh * HD;
    const float* Vb = V + (size_t)b * SEQ * KVDIM + (size_t)kvh * HD;
    float* Ob = O + (size_t)b * SEQ * DIM + (size_t)h * HD;

    // Load Q tile transposed -> Qs[d][qrow]
    {
        const float* g = Qb + (size_t)qt * BQ * DIM;
#pragma unroll
        for (int v = 0; v < 4; ++v) {
            int p = tid + v * 256;           // float4 index 0..1023
            int row = p >> 4;
            int c4 = (p & 15) << 2;
            float4 f = *(const float4*)(g + (size_t)row * DIM + c4);
            Qs[c4 + 0][row] = f.x; Qs[c4 + 1][row] = f.y;
            Qs[c4 + 2][row] = f.z; Qs[c4 + 3][row] = f.w;
        }
    }
    if (tid < BQ) { m_s[tid] = -1e30f; l_s[tid] = 0.f; }
    float acc[4][4] = {{0.f, 0.f, 0.f, 0.f}};

    for (int kt = 0; kt <= qt; ++kt) {
        __syncthreads();  // previous iteration's Ks/Vs/Ps reads done (iter0: Qs/m/l init)
        {
            const float* gk = Kb + (size_t)kt * BK * KVDIM;
            const float* gv = Vb + (size_t)kt * BK * KVDIM;
#pragma unroll
            for (int v = 0; v < 4; ++v) {
                int p = tid + v * 256;
                int row = p >> 4;
                int c4 = (p & 15) << 2;
                float4 fk = *(const float4*)(gk + (size_t)row * KVDIM + c4);
                Ks[c4 + 0][row] = fk.x; Ks[c4 + 1][row] = fk.y;
                Ks[c4 + 2][row] = fk.z; Ks[c4 + 3][row] = fk.w;
                float4 fv = *(const float4*)(gv + (size_t)row * KVDIM + c4);
                *(float4*)&Vs[row][c4] = fv;
            }
        }
        __syncthreads();

        // S = Q K^T (64x64), each thread 4x4
        float sv[4][4] = {{0.f, 0.f, 0.f, 0.f}};
#pragma unroll
        for (int dd = 0; dd < HD; ++dd) {
            float4 q4 = *(const float4*)&Qs[dd][ty << 2];
            float4 k4 = *(const float4*)&Ks[dd][tx << 2];
            float qa[4] = {q4.x, q4.y, q4.z, q4.w};
            float ka[4] = {k4.x, k4.y, k4.z, k4.w};
#pragma unroll
            for (int i = 0; i < 4; ++i)
#pragma unroll
                for (int j = 0; j < 4; ++j)
                    sv[i][j] = fmaf(qa[i], ka[j], sv[i][j]);
        }
        // scale + causal mask
        const int qg0 = qt * BQ + (ty << 2);
        const int kg0 = kt * BK + (tx << 2);
#pragma unroll
        for (int i = 0; i < 4; ++i)
#pragma unroll
            for (int j = 0; j < 4; ++j)
                sv[i][j] = (kg0 + j > qg0 + i) ? -1e30f : sv[i][j] * 0.125f;

        // row-max partials
#pragma unroll
        for (int i = 0; i < 4; ++i) {
            float mx = fmaxf(fmaxf(sv[i][0], sv[i][1]), fmaxf(sv[i][2], sv[i][3]));
            red[(ty << 2) + i][tx] = mx;
        }
        __syncthreads();
        if (tid < BQ) {
            float mo = m_s[tid];
            float mt = mo;
#pragma unroll
            for (int c = 0; c < 16; ++c) mt = fmaxf(mt, red[tid][c]);
            m_s[tid] = mt;
            al_s[tid] = __expf(mo - mt);
        }
        __syncthreads();

        // p = exp(s - m_new); write Ps k-major; rescale O; row-sum partials
#pragma unroll
        for (int i = 0; i < 4; ++i) {
            const int row = (ty << 2) + i;
            const float mn = m_s[row];
            const float a = al_s[row];
            float rs = 0.f;
#pragma unroll
            for (int j = 0; j < 4; ++j) {
                float p = __expf(sv[i][j] - mn);
                Ps[(tx << 2) + j][row] = p;
                rs += p;
                acc[i][j] *= a;
            }
            red[row][tx] = rs;
        }
        __syncthreads();
        if (tid < BQ) {
            float s = 0.f;
#pragma unroll
            for (int c = 0; c < 16; ++c) s += red[tid][c];
            l_s[tid] = l_s[tid] * al_s[tid] + s;
        }

        // O += P V
#pragma unroll
        for (int kk = 0; kk < BK; ++kk) {
            float4 p4 = *(const float4*)&Ps[kk][ty << 2];
            float4 v4 = *(const float4*)&Vs[kk][tx << 2];
            float pa[4] = {p4.x, p4.y, p4.z, p4.w};
            float va[4] = {v4.x, v4.y, v4.z, v4.w};
#pragma unroll
            for (int i = 0; i < 4; ++i)
#pragma unroll
                for (int j = 0; j < 4; ++j)
                    acc[i][j] = fmaf(pa[i], va[j], acc[i][j]);
        }
    }
    __syncthreads();  // final l_s writes visible
#pragma unroll
    for (int i = 0; i < 4; ++i) {
        const int row = (ty << 2) + i;
        float inv = 1.0f / l_s[row];
        float4 o = {acc[i][0] * inv, acc[i][1] * inv, acc[i][2] * inv, acc[i][3] * inv};
        *(float4*)(Ob + (size_t)(qt * BQ + row) * DIM + (tx << 2)) = o;
    }
}

// ---------------------------------------------------------------------------
extern "C" void kernel_launch(void* const* d_in, const int* in_sizes, int n_in,
                              void* d_out, int out_size, void* d_ws, size_t ws_size,
                              hipStream_t stream) {
    const float* X    = (const float*)d_in[0];   // [B,S,DIM]
    // d_in[1]: attention_mask — exactly causal additive; handled analytically.
    const float* cosT = (const float*)d_in[2];   // [S,HD]
    const float* sinT = (const float*)d_in[3];   // [S,HD]
    const float* Wq   = (const float*)d_in[4];   // [DIM,DIM]
    const float* Wk   = (const float*)d_in[5];   // [KVDIM,DIM]
    const float* Wv   = (const float*)d_in[6];   // [KVDIM,DIM]
    const float* Wo   = (const float*)d_in[7];   // [DIM,DIM]
    float* out = (float*)d_out;

    float* Qb  = (float*)d_ws;                                   // B*S*DIM
    float* Kb  = Qb + (size_t)BSZ * SEQ * DIM;                   // B*S*KVDIM
    float* Vb  = Kb + (size_t)BSZ * SEQ * KVDIM;                 // B*S*KVDIM
    float* ATT = Vb + (size_t)BSZ * SEQ * KVDIM;                 // B*S*DIM

    const int M = BSZ * SEQ;
    dim3 blk(256);

    gemm_nt<<<dim3(DIM / GT, M / GT), blk, 0, stream>>>(X, Wq, Qb, M, DIM, DIM);
    gemm_nt<<<dim3(KVDIM / GT, M / GT), blk, 0, stream>>>(X, Wk, Kb, M, KVDIM, DIM);
    gemm_nt<<<dim3(KVDIM / GT, M / GT), blk, 0, stream>>>(X, Wv, Vb, M, KVDIM, DIM);

    int tq = BSZ * SEQ * NH * 32;
    rope_kernel<<<dim3((tq + 255) / 256), blk, 0, stream>>>(Qb, cosT, sinT, NH, tq);
    int tk = BSZ * SEQ * NKV * 32;
    rope_kernel<<<dim3((tk + 255) / 256), blk, 0, stream>>>(Kb, cosT, sinT, NKV, tk);

    flash_attn<<<dim3(SEQ / BQ, BSZ * NH), blk, 0, stream>>>(Qb, Kb, Vb, ATT);

    gemm_nt<<<dim3(DIM / GT, M / GT), blk, 0, stream>>>(ATT, Wo, out, M, DIM, DIM);
}

// Round 2
// 850.931 us; speedup vs baseline: 4.9795x; 4.9795x over previous
//
#include <hip/hip_runtime.h>
#include <math.h>

#define BSZ 2
#define SEQ 2048
#define DIM 2048
#define NH 32
#define NKV 8
#define HD 64
#define KVDIM 512

typedef short short8 __attribute__((ext_vector_type(8)));
typedef short short4v __attribute__((ext_vector_type(4)));
typedef float f32x4 __attribute__((ext_vector_type(4)));

__device__ __forceinline__ short fbf(float x) {
    unsigned u = __float_as_uint(x);
    u = (u + 0x7fffu + ((u >> 16) & 1u)) >> 16;   // RNE f32->bf16
    return (short)u;
}

// ---------------------------------------------------------------------------
// fp32 -> bf16 convert (vectorized float4 -> 4x bf16)
// ---------------------------------------------------------------------------
__global__ __launch_bounds__(256) void f2bf(const float* __restrict__ in,
                                            short* __restrict__ out, int n4) {
    int i = blockIdx.x * 256 + threadIdx.x;
    if (i >= n4) return;
    float4 f = ((const float4*)in)[i];
    short4v s = { fbf(f.x), fbf(f.y), fbf(f.z), fbf(f.w) };
    ((short4v*)out)[i] = s;
}

// ---------------------------------------------------------------------------
// bf16 NT GEMM via MFMA: C[m,n] = sum_k A[m,k] * W[n,k], C fp32.
// 128x128 tile, 4 waves (each 64x64 = 4x4 MFMA 16x16x32), BK=32.
// LDS row stride 40 bf16 (80 B): frag reads spread evenly over bank groups.
// ---------------------------------------------------------------------------
#define GSTR 40
__global__ __launch_bounds__(256) void gemm_bf16(const short* __restrict__ A,
                                                 const short* __restrict__ W,
                                                 float* __restrict__ C,
                                                 int M, int N, int K) {
    __shared__ short As[128 * GSTR];
    __shared__ short Bs[128 * GSTR];
    const int tid = threadIdx.x;
    const int lane = tid & 63, wave = tid >> 6;
    const int l15 = lane & 15, quad = lane >> 4;
    const int m0 = blockIdx.y * 128, n0 = blockIdx.x * 128;
    const int wm = (wave >> 1) * 64, wn = (wave & 1) * 64;
    f32x4 acc[4][4] = {};
    const int row0 = tid >> 2, c0 = (tid & 3) * 8;

    for (int kb = 0; kb < K; kb += 32) {
        float4 a0 = *(const float4*)(A + (size_t)(m0 + row0) * K + kb + c0);
        float4 a1 = *(const float4*)(A + (size_t)(m0 + row0 + 64) * K + kb + c0);
        float4 b0 = *(const float4*)(W + (size_t)(n0 + row0) * K + kb + c0);
        float4 b1 = *(const float4*)(W + (size_t)(n0 + row0 + 64) * K + kb + c0);
        __syncthreads();
        *(float4*)&As[row0 * GSTR + c0] = a0;
        *(float4*)&As[(row0 + 64) * GSTR + c0] = a1;
        *(float4*)&Bs[row0 * GSTR + c0] = b0;
        *(float4*)&Bs[(row0 + 64) * GSTR + c0] = b1;
        __syncthreads();
        short8 af[4], bf8[4];
#pragma unroll
        for (int i = 0; i < 4; ++i)
            af[i] = *(const short8*)&As[(wm + i * 16 + l15) * GSTR + quad * 8];
#pragma unroll
        for (int j = 0; j < 4; ++j)
            bf8[j] = *(const short8*)&Bs[(wn + j * 16 + l15) * GSTR + quad * 8];
#pragma unroll
        for (int i = 0; i < 4; ++i)
#pragma unroll
            for (int j = 0; j < 4; ++j)
                acc[i][j] = __builtin_amdgcn_mfma_f32_16x16x32_bf16(af[i], bf8[j], acc[i][j], 0, 0, 0);
    }
#pragma unroll
    for (int i = 0; i < 4; ++i)
#pragma unroll
        for (int j = 0; j < 4; ++j)
#pragma unroll
            for (int r = 0; r < 4; ++r)
                C[(size_t)(m0 + wm + i * 16 + quad * 4 + r) * N + n0 + wn + j * 16 + l15] = acc[i][j][r];
}

// ---------------------------------------------------------------------------
// RoPE in-place on fp32 X: [BSZ, SEQ, heads, HD]
// ---------------------------------------------------------------------------
__global__ __launch_bounds__(256) void rope_kernel(float* __restrict__ X,
                                                   const float* __restrict__ cosT,
                                                   const float* __restrict__ sinT,
                                                   int heads, int total) {
    int idx = blockIdx.x * 256 + threadIdx.x;
    if (idx >= total) return;
    int d = idx & 31;
    int rh = idx >> 5;
    int s = (rh / heads) & (SEQ - 1);
    size_t base = (size_t)rh * HD;
    float x1 = X[base + d], x2 = X[base + d + 32];
    float c1 = cosT[s * HD + d], s1 = sinT[s * HD + d];
    float c2 = cosT[s * HD + d + 32], s2 = sinT[s * HD + d + 32];
    X[base + d] = fmaf(x1, c1, -x2 * s1);
    X[base + d + 32] = fmaf(x2, c2, x1 * s2);
}

// ---------------------------------------------------------------------------
// bf16 MFMA flash attention, causal, GQA (4 Q-heads per KV-head).
// Block = 4 waves, 64 Q-rows (16/wave); K-tiles of 64, kt <= qt only.
// Q frags in registers (pre-scaled by 0.125*log2e -> exp2-domain softmax).
// K in LDS natural (stride 72 bf16). V in LDS transposed with XOR-block
// swizzle (bank-even writes AND reads). P -> per-wave LDS for layout xform.
// ---------------------------------------------------------------------------
#define KSTR 72
__global__ __launch_bounds__(256) void flash_mfma(const float* __restrict__ Q,
                                                  const float* __restrict__ K,
                                                  const float* __restrict__ V,
                                                  short* __restrict__ O) {
    __shared__ short Ks[64 * KSTR];
    __shared__ short Vt[64 * 64];
    __shared__ short Ps[4][16 * KSTR];
    const int qt = blockIdx.x;
    const int bh = blockIdx.y;
    const int b = bh >> 5, h = bh & 31;
    const int kvh = h >> 2;
    const int tid = threadIdx.x;
    const int wave = tid >> 6, lane = tid & 63;
    const int l15 = lane & 15, quad = lane >> 4;

    const float* Qh = Q + (size_t)b * SEQ * DIM + (size_t)h * HD;
    const float* Kh = K + (size_t)b * SEQ * KVDIM + (size_t)kvh * HD;
    const float* Vh = V + (size_t)b * SEQ * KVDIM + (size_t)kvh * HD;
    short* Oh = O + (size_t)b * SEQ * DIM + (size_t)h * HD;

    const float qscl = 0.125f * 1.44269504088896f;  // scale * log2(e)
    short8 qf[2];
    {
        const int qr = qt * 64 + wave * 16 + l15;
#pragma unroll
        for (int kh = 0; kh < 2; ++kh) {
            const float* p = Qh + (size_t)qr * DIM + kh * 32 + quad * 8;
            float4 f0 = *(const float4*)p;
            float4 f1 = *(const float4*)(p + 4);
            short8 v;
            v[0] = fbf(f0.x * qscl); v[1] = fbf(f0.y * qscl);
            v[2] = fbf(f0.z * qscl); v[3] = fbf(f0.w * qscl);
            v[4] = fbf(f1.x * qscl); v[5] = fbf(f1.y * qscl);
            v[6] = fbf(f1.z * qscl); v[7] = fbf(f1.w * qscl);
            qf[kh] = v;
        }
    }
    f32x4 o[4] = {};
    float m[4], l[4];
#pragma unroll
    for (int r = 0; r < 4; ++r) { m[r] = -1e30f; l[r] = 0.f; }

    const int stg_row = tid >> 4;        // 0..15
    const int stg_c4 = (tid & 15) * 4;

    for (int kt = 0; kt <= qt; ++kt) {
        __syncthreads();   // prev iter's Ks/Vt reads done (incl. Ps via lgkm drain)
        // K tile: natural [row][k], bf16, packed 8B writes
#pragma unroll
        for (int v = 0; v < 4; ++v) {
            int row = stg_row + v * 16;
            float4 f = *(const float4*)(Kh + (size_t)(kt * 64 + row) * KVDIM + stg_c4);
            short4v s4 = { fbf(f.x), fbf(f.y), fbf(f.z), fbf(f.w) };
            *(short4v*)&Ks[row * KSTR + stg_c4] = s4;
        }
        // V tile: transposed Vt[d][kk] with 16B-block swizzle block^=(d&7).
        // Lane mapping (d = (tid&15)+16j) keeps writes ~2-way conflict-free.
#pragma unroll
        for (int v = 0; v < 4; ++v) {
            int kk = stg_row + v * 16;
            const float* vp = Vh + (size_t)(kt * 64 + kk) * KVDIM;
            int blk = kk >> 3, klo = kk & 7;
#pragma unroll
            for (int j = 0; j < 4; ++j) {
                int d = (tid & 15) + 16 * j;
                Vt[d * 64 + ((blk ^ (d & 7)) << 3) + klo] = fbf(vp[d]);
            }
        }
        __syncthreads();

        // S = Q K^T  (already in exp2 domain via qscl)
        f32x4 s[4] = {};
#pragma unroll
        for (int kh = 0; kh < 2; ++kh)
#pragma unroll
            for (int nt = 0; nt < 4; ++nt) {
                short8 kfrag = *(const short8*)&Ks[(nt * 16 + l15) * KSTR + kh * 32 + quad * 8];
                s[nt] = __builtin_amdgcn_mfma_f32_16x16x32_bf16(qf[kh], kfrag, s[nt], 0, 0, 0);
            }
        if (kt == qt) {   // causal mask only on diagonal tile (wave-uniform branch)
            const int rowb = qt * 64 + wave * 16 + quad * 4;
            const int colb = kt * 64 + l15;
#pragma unroll
            for (int nt = 0; nt < 4; ++nt)
#pragma unroll
                for (int r = 0; r < 4; ++r)
                    if (colb + nt * 16 > rowb + r) s[nt][r] = -1e30f;
        }

        // online softmax, in-register; rows live in 16-lane quad groups
        float mx[4], al[4], rs[4];
#pragma unroll
        for (int r = 0; r < 4; ++r)
            mx[r] = fmaxf(fmaxf(s[0][r], s[1][r]), fmaxf(s[2][r], s[3][r]));
#pragma unroll
        for (int off = 1; off <= 8; off <<= 1)
#pragma unroll
            for (int r = 0; r < 4; ++r)
                mx[r] = fmaxf(mx[r], __shfl_xor(mx[r], off));
#pragma unroll
        for (int r = 0; r < 4; ++r) {
            float mn = fmaxf(m[r], mx[r]);
            al[r] = exp2f(m[r] - mn);
            m[r] = mn;
            rs[r] = 0.f;
        }
#pragma unroll
        for (int nt = 0; nt < 4; ++nt)
#pragma unroll
            for (int r = 0; r < 4; ++r) {
                float p = exp2f(s[nt][r] - m[r]);
                s[nt][r] = p;
                rs[r] += p;
            }
#pragma unroll
        for (int off = 1; off <= 8; off <<= 1)
#pragma unroll
            for (int r = 0; r < 4; ++r)
                rs[r] += __shfl_xor(rs[r], off);
#pragma unroll
        for (int r = 0; r < 4; ++r) l[r] = l[r] * al[r] + rs[r];
#pragma unroll
        for (int dt = 0; dt < 4; ++dt)
#pragma unroll
            for (int r = 0; r < 4; ++r) o[dt][r] *= al[r];

        // P (C-layout) -> per-wave LDS (A-layout rows)
#pragma unroll
        for (int nt = 0; nt < 4; ++nt)
#pragma unroll
            for (int r = 0; r < 4; ++r)
                Ps[wave][(quad * 4 + r) * KSTR + nt * 16 + l15] = fbf(s[nt][r]);

        // O += P V
#pragma unroll
        for (int kh = 0; kh < 2; ++kh) {
            short8 pf = *(const short8*)&Ps[wave][l15 * KSTR + kh * 32 + quad * 8];
#pragma unroll
            for (int dt = 0; dt < 4; ++dt) {
                short8 vf = *(const short8*)&Vt[(dt * 16 + l15) * 64 + (((kh * 4 + quad) ^ (l15 & 7)) << 3)];
                o[dt] = __builtin_amdgcn_mfma_f32_16x16x32_bf16(pf, vf, o[dt], 0, 0, 0);
            }
        }
    }
    // epilogue: O/l -> bf16 ATT
#pragma unroll
    for (int r = 0; r < 4; ++r) {
        float inv = 1.0f / l[r];
        int row = qt * 64 + wave * 16 + quad * 4 + r;
#pragma unroll
        for (int dt = 0; dt < 4; ++dt)
            Oh[(size_t)row * DIM + dt * 16 + l15] = fbf(o[dt][r] * inv);
    }
}

// ---------------------------------------------------------------------------
extern "C" void kernel_launch(void* const* d_in, const int* in_sizes, int n_in,
                              void* d_out, int out_size, void* d_ws, size_t ws_size,
                              hipStream_t stream) {
    const float* X    = (const float*)d_in[0];
    const float* cosT = (const float*)d_in[2];
    const float* sinT = (const float*)d_in[3];
    const float* Wq   = (const float*)d_in[4];
    const float* Wk   = (const float*)d_in[5];
    const float* Wv   = (const float*)d_in[6];
    const float* Wo   = (const float*)d_in[7];

    char* ws = (char*)d_ws;
    float* Kf   = (float*)(ws);                       // 8,388,608 B
    float* Vf   = (float*)(ws + 8388608);             // 8,388,608 B
    short* Xb   = (short*)(ws + 16777216);            // 16,777,216 B
    short* ATTb = (short*)(ws + 33554432);            // 16,777,216 B
    short* Wqob = (short*)(ws + 50331648);            // 8,388,608 B (Wq, later Wo)
    short* Wkb  = (short*)(ws + 58720256);            // 2,097,152 B
    short* Wvb  = (short*)(ws + 60817408);            // 2,097,152 B
    float* Qf   = (float*)d_out;                      // Q fp32 scratch (dead after flash)

    const int M = BSZ * SEQ;
    dim3 blk(256);

    int nx4 = BSZ * SEQ * DIM / 4;
    f2bf<<<dim3(nx4 / 256), blk, 0, stream>>>(X, Xb, nx4);
    int nwq4 = DIM * DIM / 4;
    f2bf<<<dim3(nwq4 / 256), blk, 0, stream>>>(Wq, Wqob, nwq4);
    gemm_bf16<<<dim3(DIM / 128, M / 128), blk, 0, stream>>>(Xb, Wqob, Qf, M, DIM, DIM);

    int nwk4 = KVDIM * DIM / 4;
    f2bf<<<dim3(nwk4 / 256), blk, 0, stream>>>(Wk, Wkb, nwk4);
    gemm_bf16<<<dim3(KVDIM / 128, M / 128), blk, 0, stream>>>(Xb, Wkb, Kf, M, KVDIM, DIM);
    f2bf<<<dim3(nwk4 / 256), blk, 0, stream>>>(Wv, Wvb, nwk4);
    gemm_bf16<<<dim3(KVDIM / 128, M / 128), blk, 0, stream>>>(Xb, Wvb, Vf, M, KVDIM, DIM);

    int tq = BSZ * SEQ * NH * 32;
    rope_kernel<<<dim3(tq / 256), blk, 0, stream>>>(Qf, cosT, sinT, NH, tq);
    int tk = BSZ * SEQ * NKV * 32;
    rope_kernel<<<dim3(tk / 256), blk, 0, stream>>>(Kf, cosT, sinT, NKV, tk);

    flash_mfma<<<dim3(SEQ / 64, BSZ * NH), blk, 0, stream>>>(Qf, Kf, Vf, ATTb);

    f2bf<<<dim3(nwq4 / 256), blk, 0, stream>>>(Wo, Wqob, nwq4);
    gemm_bf16<<<dim3(DIM / 128, M / 128), blk, 0, stream>>>(ATTb, Wqob, (float*)d_out, M, DIM, DIM);
}